// Round 5
// baseline (312.745 us; speedup 1.0000x reference)
//
#include <hip/hip_runtime.h>

// Problem constants
// B=16, CI=CO=32, H=W=256, K0=K1=M=32, KAPPA=8, NPARA=7
// Kept modes: ky rows j in [0,64): ky = j (j<32) or j-64 (j>=32); kx cols 0..31
//
// Pipeline (raw/unnormalized DFTs; 1/65536 ortho factor applied at final store):
//  K1 (k_fwd, f16 MFMA):  per p=(b,ci): row-DFT (x -> Xw in LDS, sign-expanded)
//                         then col-DFT -> Xf16[p][j][kx] packed f16
//  K2 (k_mixB, f32 VALU): Ff16[q][j][kx] = sum_ci Xf16 * (W + s_b*We)
//  K3 (k_invF, f16 MFMA): per q: G[h][2kx+c] = sum_j Ff16 * e^{+i...} (LDS only),
//                         then out[q][h][w] = (1/65536) * sum_col G * Ftab
//                         (both inverse GEMMs computed TRANSPOSED: A/B operands swapped
//                          so D-fragments land with 4 consecutive outputs per lane ->
//                          packed ds_write_b64 / float4 global stores)

typedef _Float16 f16;
typedef _Float16 f16x8 __attribute__((ext_vector_type(8)));
typedef float f32x4 __attribute__((ext_vector_type(4)));

static __device__ __forceinline__ float2 upk(uint u) {
    union { uint x; f16 h[2]; } c; c.x = u;
    return make_float2((float)c.h[0], (float)c.h[1]);
}
static __device__ __forceinline__ uint pk2(float r, float i) {
    union { uint x; f16 h[2]; } c; c.h[0] = (f16)r; c.h[1] = (f16)i;
    return c.x;
}

// Tables:
//  Etab [h][2j]    = cos(2*pi*ky_j*h/256), [2j+1] = sin(...)     [256][128] f16 (invF B-phase)
//  Ftabt[w][2k]    = c_k*cos(2*pi*k*w/256), [2k+1] = -c_k*sin()  [256][64]  f16 (invF C-phase)
//  Etab2[j][h]     = cos(2*pi*ky_j*h/256)  (PLANAR K: cos plane) [64][512]  f16 (fwd col A)
//       [j][256+h] = sin(2*pi*ky_j*h/256)  (sin plane)
//  Tt  [2kx][w]    = cos(2*pi*kx*w/256), [2kx+1][w] = -sin(...)  [64][256]  f16 (fwd row B^T)
__global__ void k_tabs(f16* __restrict__ Etab, f16* __restrict__ Ftabt,
                       f16* __restrict__ Etab2, f16* __restrict__ Tt) {
    const int h = blockIdx.x;     // 0..255 (plays w where relevant)
    const int tid = threadIdx.x;  // 0..127
    if (tid < 64) {
        const int j = tid;
        const int ky = (j < 32) ? j : j - 64;
        float s, c;
        sincospif((float)(ky * h) / 128.0f, &s, &c);
        Etab[h * 128 + 2 * j] = (f16)c;
        Etab[h * 128 + 2 * j + 1] = (f16)s;
        Etab2[j * 512 + h] = (f16)c;        // cos plane (K = h)
        Etab2[j * 512 + 256 + h] = (f16)s;  // sin plane (K = 256+h)
    } else if (tid < 96) {
        const int k = tid - 64;
        const float ck = (k == 0) ? 1.0f : 2.0f;
        float s, c;
        sincospif((float)(k * h) / 128.0f, &s, &c);
        Ftabt[h * 64 + 2 * k] = (f16)(ck * c);
        Ftabt[h * 64 + 2 * k + 1] = (f16)(-ck * s);
    } else {
        const int kx = tid - 96;
        float s, c;
        sincospif((float)(kx * h) / 128.0f, &s, &c);
        Tt[(2 * kx) * 256 + h] = (f16)c;
        Tt[(2 * kx + 1) * 256 + h] = (f16)(-s);
    }
}

// K1 (k_fwd): fused row+col DFT per p=(b,ci). 512 blocks x 256 threads (= 2 blocks/CU).
__global__ __launch_bounds__(256) void k_fwd(const float* __restrict__ x,
                                             const f16* __restrict__ Tt,
                                             const f16* __restrict__ Etab2,
                                             f16* __restrict__ Xf16) {
    __shared__ __align__(16) f16 Bt[64 * 520];  // 66.6 KB, row stride 520 f16 (65x16B)
    const int tid = threadIdx.x;
    const long p = blockIdx.x;
    const int wv = tid >> 6, lane = tid & 63;
    const int l15 = lane & 15, lk = lane >> 4;

    // ---- Phase 1: row DFT (wave handles 64 h-rows = 4 m-tiles) ----
    {
        f32x4 acc[4][4];
#pragma unroll
        for (int mt = 0; mt < 4; ++mt)
#pragma unroll
            for (int nt = 0; nt < 4; ++nt)
                acc[mt][nt] = (f32x4){0.0f, 0.0f, 0.0f, 0.0f};

        const float* xbase = x + (p * 256 + wv * 64 + l15) * 256 + lk * 8;
        const f16* tbase = Tt + l15 * 256 + lk * 8;

#pragma unroll 4
        for (int ks = 0; ks < 8; ++ks) {
            f16x8 a[4], b[4];
#pragma unroll
            for (int mt = 0; mt < 4; ++mt) {
                const float4 u = *(const float4*)(xbase + mt * 4096 + ks * 32);
                const float4 v = *(const float4*)(xbase + mt * 4096 + ks * 32 + 4);
                a[mt][0] = (f16)u.x; a[mt][1] = (f16)u.y;
                a[mt][2] = (f16)u.z; a[mt][3] = (f16)u.w;
                a[mt][4] = (f16)v.x; a[mt][5] = (f16)v.y;
                a[mt][6] = (f16)v.z; a[mt][7] = (f16)v.w;
            }
#pragma unroll
            for (int nt = 0; nt < 4; ++nt)
                b[nt] = *(const f16x8*)(tbase + nt * 4096 + ks * 32);
#pragma unroll
            for (int mt = 0; mt < 4; ++mt)
#pragma unroll
                for (int nt = 0; nt < 4; ++nt)
                    acc[mt][nt] = __builtin_amdgcn_mfma_f32_16x16x32_f16(
                        a[mt], b[nt], acc[mt][nt], 0, 0, 0);
        }

        // scatter D -> Bt (planar layout). Lane owns n = nt*16+l15,
        // h = wv*64 + mt*16 + lk*4 + r  (r=0..3 consecutive -> packed b64 writes).
        const int n = l15;
        const uint m = (n & 1) ? 0u : 0x80008000u;  // write2 sign: even n stores -v
#pragma unroll
        for (int mt = 0; mt < 4; ++mt) {
            const int H0 = wv * 64 + mt * 16 + lk * 4;
#pragma unroll
            for (int nt = 0; nt < 4; ++nt) {
                const int nn = nt * 16 + l15;
                const uint p0 = pk2(acc[mt][nt][0], acc[mt][nt][1]);
                const uint p1 = pk2(acc[mt][nt][2], acc[mt][nt][3]);
                *(uint2*)(Bt + nn * 520 + H0) = make_uint2(p0, p1);
                *(uint2*)(Bt + (nn ^ 1) * 520 + 256 + H0) = make_uint2(p0 ^ m, p1 ^ m);
            }
        }
    }
    __syncthreads();

    // ---- Phase 2: col DFT (wave handles 16 j-rows) ----
    {
        f32x4 acc[4];
#pragma unroll
        for (int nt = 0; nt < 4; ++nt) acc[nt] = (f32x4){0.0f, 0.0f, 0.0f, 0.0f};

        const f16* abase = Etab2 + (wv * 16 + l15) * 512 + lk * 8;  // global, L2-hot
#pragma unroll
        for (int ks = 0; ks < 16; ++ks) {
            const f16x8 a = *(const f16x8*)(abase + ks * 32);
            f16x8 b[4];
#pragma unroll
            for (int nt = 0; nt < 4; ++nt)
                b[nt] = *(const f16x8*)(Bt + (nt * 16 + l15) * 520 + ks * 32 + lk * 8);
#pragma unroll
            for (int nt = 0; nt < 4; ++nt)
                acc[nt] = __builtin_amdgcn_mfma_f32_16x16x32_f16(a, b[nt], acc[nt], 0, 0, 0);
        }

        f16* obase = Xf16 + p * 4096;
#pragma unroll
        for (int nt = 0; nt < 4; ++nt)
#pragma unroll
            for (int r = 0; r < 4; ++r)
                obase[(wv * 16 + lk * 4 + r) * 64 + nt * 16 + l15] = (f16)acc[nt][r];
    }
}

// K2 (mixB): block = (cog 8)*(corner 2)*(jj 32) = 512 blocks.
__global__ __launch_bounds__(256) void k_mixB(const f16* __restrict__ Xf16,
                                              const float* __restrict__ fs,
                                              const float* __restrict__ w0,
                                              const float* __restrict__ w1,
                                              const float* __restrict__ we0,
                                              const float* __restrict__ we1,
                                              f16* __restrict__ Ff16) {
    __shared__ __align__(16) float4 Wl[4096];  // 64 KB: rows 0..127 = W, 128..255 = We
    const int tid = threadIdx.x;
    const int bid = blockIdx.x;
    const int cog = bid >> 6;            // 0..7 (co group of 4)
    const int corner = (bid >> 5) & 1;
    const int jj = bid & 31;
    const int j = corner * 32 + jj;

    {   // stage: t = tid>>7 (0:W 1:We), ci = (tid>>2)&31, co = tid&3
        const int t = tid >> 7, ci = (tid >> 2) & 31, co = tid & 3;
        const float* Wt = (t == 0) ? (corner ? w1 : w0) : (corner ? we1 : we0);
        const float4* src =
            (const float4*)(Wt + ((long)(ci * 32 + cog * 4 + co) * 2048 + jj * 64));
        const int m = tid & 15;
#pragma unroll
        for (int i = 0; i < 16; ++i) Wl[tid * 16 + (i ^ m)] = src[i];
    }
    __syncthreads();

    const int b = tid >> 4, kxp = tid & 15;
    const int kx0 = 2 * kxp;

    float s[2];
#pragma unroll
    for (int e = 0; e < 2; ++e) {
        const int v = kx0 + e, u = jj;
        int idx;
        if (u < 8 && v < 8) idx = 0;
        else if (u < 16 && v < 16) idx = (u < 8) ? 1 : ((v < 8) ? 2 : 3);
        else idx = (u < 16) ? 4 : ((v < 16) ? 5 : 6);
        s[e] = fs[b * 7 + idx];
    }

    float aW[4][4] = {}, aE[4][4] = {};  // [co][{re0,im0,re1,im1}]
    const uint* xb = (const uint*)Xf16 + (long)(b * 32) * 2048 + j * 32 + kxp * 2;

    for (int ci = 0; ci < 32; ++ci) {
        const uint2 xu = *(const uint2*)(xb + ci * 2048);
        const float2 x0 = upk(xu.x), x1 = upk(xu.y);
        const int rbase = ci * 4;
#pragma unroll
        for (int co = 0; co < 4; ++co) {
            const int rw = rbase + co;
            const int sl = kxp ^ (rw & 15);
            const float4 wv = Wl[rw * 16 + sl];
            const float4 ev = Wl[(128 + rw) * 16 + sl];
            aW[co][0] += x0.x * wv.x - x0.y * wv.y;
            aW[co][1] += x0.x * wv.y + x0.y * wv.x;
            aW[co][2] += x1.x * wv.z - x1.y * wv.w;
            aW[co][3] += x1.x * wv.w + x1.y * wv.z;
            aE[co][0] += x0.x * ev.x - x0.y * ev.y;
            aE[co][1] += x0.x * ev.y + x0.y * ev.x;
            aE[co][2] += x1.x * ev.z - x1.y * ev.w;
            aE[co][3] += x1.x * ev.w + x1.y * ev.z;
        }
    }

    uint* ofb = (uint*)Ff16;
#pragma unroll
    for (int co = 0; co < 4; ++co) {
        const long q = b * 32 + cog * 4 + co;
        uint2 o;
        o.x = pk2(aW[co][0] + s[0] * aE[co][0], aW[co][1] + s[0] * aE[co][1]);
        o.y = pk2(aW[co][2] + s[1] * aE[co][2], aW[co][3] + s[1] * aE[co][3]);
        *(uint2*)(ofb + q * 2048 + j * 32 + kxp * 2) = o;
    }
}

// K3 (invF): fused inverse per q. 512 blocks x 256 threads (= 2 blocks/CU).
// Phase B (TRANSPOSED): D'[n][h] = Ft[n][K] x Etab^T[K][h]; lane holds 4 consecutive n
//          at fixed h -> packed uint2 ds-writes into Gs[h][n0..n0+3].
// Phase C (TRANSPOSED): D'[w][h] = Ftabt[w][col] x G^T[col][h]; lane holds 4 consecutive
//          w at fixed h -> float4 global stores.
__global__ __launch_bounds__(256) void k_invF(const f16* __restrict__ Ff16,
                                              const f16* __restrict__ Etab,
                                              const f16* __restrict__ Ftabt,
                                              float* __restrict__ out) {
    __shared__ __align__(16) f16 Ft[64 * 136];   // F' transposed [n][K], pad 128->136
    __shared__ __align__(16) f16 Gs[256 * 72];   // G [h][col], pad 64->72
    const int tid = threadIdx.x;
    const long q = blockIdx.x;
    const int wv = tid >> 6, lane = tid & 63;
    const int l15 = lane & 15, lk = lane >> 4;

    {   // stage F't from packed Ff16 (2048 u32 per q): thread handles 8 u32
        const uint4* src = (const uint4*)(Ff16 + q * 4096);
        uint* B32 = (uint*)Ft;
#pragma unroll
        for (int i = 0; i < 2; ++i) {
            const uint4 v = src[tid * 2 + i];
            const uint a4[4] = {v.x, v.y, v.z, v.w};
#pragma unroll
            for (int c = 0; c < 4; ++c) {
                const int idx = tid * 8 + i * 4 + c;  // u32 idx: j = idx>>5, kx = idx&31
                const int jr = idx >> 5, kx = idx & 31;
                const uint a = a4[c];
                B32[(2 * kx) * 68 + jr] = a ^ 0x80000000u;           // (re, -im)
                B32[(2 * kx + 1) * 68 + jr] = (a >> 16) | (a << 16); // (im,  re)
            }
        }
    }
    __syncthreads();

    // ---- Phase B (transposed): acc[ntile][ht], A' = Ft rows (n), B' = Etab rows (h) ----
    {
        f32x4 acc[4][4];
#pragma unroll
        for (int mt = 0; mt < 4; ++mt)
#pragma unroll
            for (int nt = 0; nt < 4; ++nt)
                acc[mt][nt] = (f32x4){0.0f, 0.0f, 0.0f, 0.0f};

#pragma unroll
        for (int ks = 0; ks < 4; ++ks) {
            f16x8 a[4], b[4];
#pragma unroll
            for (int mt = 0; mt < 4; ++mt)  // mt = n-tile
                a[mt] = *(const f16x8*)(&Ft[(mt * 16 + l15) * 136 + ks * 32 + lk * 8]);
#pragma unroll
            for (int nt = 0; nt < 4; ++nt)  // nt = h-tile
                b[nt] = *(const f16x8*)(Etab + (wv * 64 + nt * 16 + l15) * 128 +
                                        ks * 32 + lk * 8);
#pragma unroll
            for (int mt = 0; mt < 4; ++mt)
#pragma unroll
                for (int nt = 0; nt < 4; ++nt)
                    acc[mt][nt] = __builtin_amdgcn_mfma_f32_16x16x32_f16(
                        a[mt], b[nt], acc[mt][nt], 0, 0, 0);
        }

        // D'[row = n = mt*16 + lk*4 + r][col = h = wv*64 + nt*16 + l15]
#pragma unroll
        for (int mt = 0; mt < 4; ++mt)
#pragma unroll
            for (int nt = 0; nt < 4; ++nt) {
                const int h = wv * 64 + nt * 16 + l15;
                const int n0 = mt * 16 + lk * 4;
                const uint p0 = pk2(acc[mt][nt][0], acc[mt][nt][1]);
                const uint p1 = pk2(acc[mt][nt][2], acc[mt][nt][3]);
                *(uint2*)(Gs + h * 72 + n0) = make_uint2(p0, p1);
            }
    }
    __syncthreads();

    // ---- Phase C (transposed): wave owns h-block wv*64..+63; A' = Ftabt (w), B' = Gs (h) ----
    {
        const int hb = wv * 64;
        f16x8 bG[4][2];
#pragma unroll
        for (int ht = 0; ht < 4; ++ht)
#pragma unroll
            for (int ks = 0; ks < 2; ++ks)
                bG[ht][ks] =
                    *(const f16x8*)(Gs + (hb + ht * 16 + l15) * 72 + ks * 32 + lk * 8);

        float* obase = out + q * 65536 + (long)hb * 256;

#pragma unroll 1
        for (int g = 0; g < 4; ++g) {  // 4 groups of 64 w-columns
            f32x4 acc[4][4];  // [wt][ht]
#pragma unroll
            for (int wt = 0; wt < 4; ++wt)
#pragma unroll
                for (int ht = 0; ht < 4; ++ht)
                    acc[wt][ht] = (f32x4){0.0f, 0.0f, 0.0f, 0.0f};

            const f16* abase = Ftabt + (g * 64 + l15) * 64 + lk * 8;
#pragma unroll
            for (int wt = 0; wt < 4; ++wt)
#pragma unroll
                for (int ks = 0; ks < 2; ++ks) {
                    const f16x8 a = *(const f16x8*)(abase + wt * 1024 + ks * 32);
#pragma unroll
                    for (int ht = 0; ht < 4; ++ht)
                        acc[wt][ht] = __builtin_amdgcn_mfma_f32_16x16x32_f16(
                            a, bG[ht][ks], acc[wt][ht], 0, 0, 0);
                }

            // D'[row = w = g*64 + wt*16 + lk*4 + r][col = h = hb + ht*16 + l15]
#pragma unroll
            for (int wt = 0; wt < 4; ++wt)
#pragma unroll
                for (int ht = 0; ht < 4; ++ht) {
                    float* o = obase + (ht * 16 + l15) * 256 + g * 64 + wt * 16 + lk * 4;
                    *(float4*)o = make_float4(acc[wt][ht][0] * 0x1p-16f,
                                              acc[wt][ht][1] * 0x1p-16f,
                                              acc[wt][ht][2] * 0x1p-16f,
                                              acc[wt][ht][3] * 0x1p-16f);
                }
        }
    }
}

extern "C" void kernel_launch(void* const* d_in, const int* in_sizes, int n_in,
                              void* d_out, int out_size, void* d_ws, size_t ws_size,
                              hipStream_t stream) {
    (void)in_sizes; (void)n_in; (void)out_size; (void)ws_size;
    const float* x   = (const float*)d_in[0];
    const float* fs  = (const float*)d_in[1];
    const float* w0  = (const float*)d_in[2];
    const float* w1  = (const float*)d_in[3];
    const float* we0 = (const float*)d_in[4];
    const float* we1 = (const float*)d_in[5];
    float* out = (float*)d_out;
    float* ws = (float*)d_ws;

    f16* Etab   = (f16*)ws;                        // 64 KB
    f16* Ftabt  = (f16*)(ws + 16384);              // 32 KB
    f16* Etab2  = (f16*)(ws + 24576);              // 64 KB (planar cos/sin)
    f16* Tt     = (f16*)(ws + 40960);              // 32 KB
    f16* Xf16   = (f16*)(ws + 49152);              // 4 MB packed [p][j][kx]
    f16* Ff16   = (f16*)(ws + 49152 + 1048576);    // 4 MB packed [q][j][kx]

    k_tabs <<<256, 128, 0, stream>>>(Etab, Ftabt, Etab2, Tt);
    k_fwd  <<<512, 256, 0, stream>>>(x, Tt, Etab2, Xf16);
    k_mixB <<<512, 256, 0, stream>>>(Xf16, fs, w0, w1, we0, we1, Ff16);
    k_invF <<<512, 256, 0, stream>>>(Ff16, Etab, Ftabt, out);
}